// Round 1
// baseline (378.610 us; speedup 1.0000x reference)
//
#include <hip/hip_runtime.h>

// 3x3 SAME conv + bias + ReLU, N=32, Cin=Cout=256, H=W=56, fp32 in/out.
// Implicit-GEMM in bf16 MFMA: C[co][pix] = sum_{tap,ci} Wb[co][tap*256+ci] * X[...].
// BM=128 x BN=64 x BK=64, 4 waves, 2-phase prefetch pipeline, XOR-swizzled LDS.

#define GLOBAL_AS __attribute__((address_space(1)))
#define LDS_AS __attribute__((address_space(3)))

typedef __attribute__((ext_vector_type(8))) short short8;
typedef __attribute__((ext_vector_type(4))) float f32x4;

#define CIN   256
#define COUTC 256
#define HWS   3136      // 56*56
#define KTOT  2304      // CIN*9
#define NSTEP 36        // KTOT/64
#define WROWB 4608      // KTOT*2 bytes per weight row

__device__ __forceinline__ unsigned short f2bf(float f) {
  unsigned u = __builtin_bit_cast(unsigned, f);
  return (unsigned short)((u + 0x7fffu + ((u >> 16) & 1u)) >> 16);  // RNE
}

// Repack weights OIHW fp32 -> bf16 [co][tap*256+ci]
__global__ void wcvt_kernel(const float* __restrict__ w, unsigned short* __restrict__ wb) {
  int o = blockIdx.x * 256 + threadIdx.x;   // 0 .. 589823
  int co = o / KTOT;
  int rr = o - co * KTOT;
  int tap = rr >> 8;
  int ci = rr & 255;
  wb[o] = f2bf(w[co * KTOT + ci * 9 + tap]);
}

__global__ __launch_bounds__(256, 3) void conv_kernel(
    const float* __restrict__ x, const unsigned char* __restrict__ wb,
    const float* __restrict__ bias, float* __restrict__ out) {
  // LDS: A dbuf 2x16KB at 0, B dbuf 2x8KB at 32768
  __shared__ __align__(16) unsigned char smem[49152];

  const int bid  = blockIdx.x;
  const int tile = bid >> 1;              // 1568 pixel tiles
  const int co0  = (bid & 1) * 128;       // which co half
  const int n    = tile / 49;
  const int p0   = (tile - n * 49) * 64;  // base pixel in image (3136 = 49*64)

  const int t    = threadIdx.x;
  const int lane = t & 63;
  const int wave = t >> 6;
  const int wm   = wave & 1;              // co 64-half within BM=128
  const int wn   = wave >> 1;             // pix 32-half within BN=64

  // B-staging identity: thread -> (pixel lane, k-octet selector)
  const int pl     = lane;                // 0..63
  const int octsel = wave;                // 0..3, handles octets {octsel, octsel+4}
  const int p_img  = p0 + pl;
  const int ph     = p_img / 56;
  const int pw     = p_img - ph * 56;
  const float* xn  = x + (size_t)n * (CIN * HWS);
  const unsigned swzp = (unsigned)((pl & 7) << 4);

  f32x4 acc[4][2];
  const f32x4 zero4 = {0.f, 0.f, 0.f, 0.f};
#pragma unroll
  for (int m = 0; m < 4; ++m)
#pragma unroll
    for (int nn = 0; nn < 2; ++nn) acc[m][nn] = zero4;

  // ---- A stage: weights bf16 via global_load_lds, pre-swizzled source ----
  auto stageA = [&](int s, int buf) {
#pragma unroll
    for (int i = 0; i < 4; ++i) {
      unsigned o   = (unsigned)((wave * 4 + i) * 1024 + lane * 16);  // linear LDS byte
      unsigned row = o >> 7;        // co row within tile (128B = 64 bf16 per row)
      unsigned sb  = o & 127;       // slot byte within row
      const unsigned char* g = wb + (size_t)(co0 + row) * WROWB + (unsigned)s * 128
                                  + (sb ^ ((row & 7) << 4));
      unsigned char* l = smem + buf * 16384 + (wave * 4 + i) * 1024;  // wave-uniform base
      __builtin_amdgcn_global_load_lds((const GLOBAL_AS unsigned int*)g,
                                       (LDS_AS unsigned int*)l, 16, 0, 0);
    }
  };

  // ---- B stage: x gather fp32 -> bf16 -> swizzled LDS [pix][64] ----
  auto stageB = [&](int s, int buf) {
    const int tap = s >> 2;                 // same (kh,kw) for whole K-step
    const int dh  = tap / 3 - 1;
    const int dw  = tap - (tap / 3) * 3 - 1;
    const int c0  = (s & 3) * 64;
    const int hh  = ph + dh;
    const int wwi = pw + dw;
    const bool valid = ((unsigned)hh < 56u) && ((unsigned)wwi < 56u);
    const float* s0 = xn + (size_t)(c0 + octsel * 8) * HWS + hh * 56 + wwi;

    float f[16];
    if (valid) {
#pragma unroll
      for (int j = 0; j < 8; ++j) {
        f[j]     = s0[(size_t)j * HWS];
        f[j + 8] = s0[(size_t)(j + 32) * HWS];
      }
    } else {
#pragma unroll
      for (int j = 0; j < 16; ++j) f[j] = 0.f;
    }
    short8 v0, v1;
#pragma unroll
    for (int j = 0; j < 8; ++j) {
      v0[j] = (short)f2bf(f[j]);
      v1[j] = (short)f2bf(f[j + 8]);
    }
    unsigned char* bB = smem + 32768 + buf * 8192;
    *(short8*)(bB + pl * 128 + ((unsigned)(octsel * 16) ^ swzp))       = v0;
    *(short8*)(bB + pl * 128 + ((unsigned)((octsel + 4) * 16) ^ swzp)) = v1;
  };

  // ---- compute one K-step (64) from buffer ----
  auto compute = [&](int buf) {
    const unsigned char* bA = smem + buf * 16384;
    const unsigned char* bB = smem + 32768 + buf * 8192;
    const int rl = lane & 15;
    const int kq = lane >> 4;
    const unsigned swz = (unsigned)((rl & 7) << 4);
#pragma unroll
    for (int ks = 0; ks < 2; ++ks) {
      const unsigned kb = (unsigned)(ks * 64 + kq * 16);
      short8 a[4], b[2];
#pragma unroll
      for (int m = 0; m < 4; ++m)
        a[m] = *(const short8*)(bA + (wm * 64 + m * 16 + rl) * 128 + (kb ^ swz));
#pragma unroll
      for (int nn = 0; nn < 2; ++nn)
        b[nn] = *(const short8*)(bB + (wn * 32 + nn * 16 + rl) * 128 + (kb ^ swz));
#pragma unroll
      for (int m = 0; m < 4; ++m)
#pragma unroll
        for (int nn = 0; nn < 2; ++nn)
          acc[m][nn] = __builtin_amdgcn_mfma_f32_16x16x32_bf16(a[m], b[nn], acc[m][nn], 0, 0, 0);
    }
  };

  // ---- 2-phase pipeline ----
  stageA(0, 0);
  stageB(0, 0);
  __syncthreads();
  for (int s = 0; s < NSTEP; ++s) {
    const int cur = s & 1;
    if (s < NSTEP - 1) {
      stageA(s + 1, cur ^ 1);
      stageB(s + 1, cur ^ 1);
    }
    compute(cur);
    __syncthreads();
  }

  // ---- epilogue: bias + ReLU, C/D map: col=lane&15, row=(lane>>4)*4+j ----
  {
    const int rl = lane & 15;
    const int kq = lane >> 4;
    float* outn = out + (size_t)n * (COUTC * HWS);
#pragma unroll
    for (int m = 0; m < 4; ++m) {
      const int row = co0 + wm * 64 + m * 16 + kq * 4;
#pragma unroll
      for (int nn = 0; nn < 2; ++nn) {
        const int col = p0 + wn * 32 + nn * 16 + rl;
        float* po = outn + (size_t)row * HWS + col;
#pragma unroll
        for (int j = 0; j < 4; ++j) {
          float v = acc[m][nn][j] + bias[row + j];
          po[(size_t)j * HWS] = fmaxf(v, 0.f);
        }
      }
    }
  }
}

extern "C" void kernel_launch(void* const* d_in, const int* in_sizes, int n_in,
                              void* d_out, int out_size, void* d_ws, size_t ws_size,
                              hipStream_t stream) {
  const float* x    = (const float*)d_in[0];
  const float* w    = (const float*)d_in[1];
  const float* bias = (const float*)d_in[2];
  float* out        = (float*)d_out;
  unsigned short* wb = (unsigned short*)d_ws;  // needs 1,179,648 B

  hipLaunchKernelGGL(wcvt_kernel, dim3(2304), dim3(256), 0, stream, w, wb);
  hipLaunchKernelGGL(conv_kernel, dim3(3136), dim3(256), 0, stream,
                     x, (const unsigned char*)d_ws, bias, out);
}

// Round 2
// 196.274 us; speedup vs baseline: 1.9290x; 1.9290x over previous
//
#include <hip/hip_runtime.h>

// 3x3 SAME conv + bias + ReLU, N=32, Cin=Cout=256, H=W=56, fp32 in/out.
// Implicit-GEMM bf16 MFMA. v2: BM=256 (all co) x BN=64 pix, 8 waves,
// K-order = channel-chunk outer / tap inner (L2-hot x reuse),
// XCD-chunked block swizzle, XOR-swizzled LDS, 2-phase prefetch.

#define GLOBAL_AS __attribute__((address_space(1)))
#define LDS_AS __attribute__((address_space(3)))

typedef __attribute__((ext_vector_type(8))) short short8;
typedef __attribute__((ext_vector_type(4))) float f32x4;

#define CIN   256
#define HWS   3136      // 56*56
#define KTOT  2304      // CIN*9
#define WROWB 4608      // KTOT*2 bytes per weight row
#define NSTEP 36        // 4 chunks * 9 taps

__device__ __forceinline__ unsigned short f2bf(float f) {
  unsigned u = __builtin_bit_cast(unsigned, f);
  return (unsigned short)((u + 0x7fffu + ((u >> 16) & 1u)) >> 16);  // RNE
}

// Repack weights OIHW fp32 -> bf16 [co][tap*256+ci]
__global__ void wcvt_kernel(const float* __restrict__ w, unsigned short* __restrict__ wb) {
  int o = blockIdx.x * 256 + threadIdx.x;
  int co = o / KTOT;
  int rr = o - co * KTOT;
  int tap = rr >> 8;
  int ci = rr & 255;
  wb[o] = f2bf(w[co * KTOT + ci * 9 + tap]);
}

__global__ __launch_bounds__(512, 4) void conv_kernel(
    const float* __restrict__ x, const unsigned char* __restrict__ wb,
    const float* __restrict__ bias, float* __restrict__ out) {
  // LDS: A dbuf 2x32KB at 0, B dbuf 2x8KB at 65536
  __shared__ __align__(16) unsigned char smem[81920];

  const int bid  = blockIdx.x;
  const int tile = (bid & 7) * 196 + (bid >> 3);  // XCD-chunked, bijective (1568=8*196)
  const int n    = tile / 49;
  const int p0   = (tile - n * 49) * 64;          // base pixel (3136 = 49*64)

  const int t    = threadIdx.x;
  const int lane = t & 63;
  const int wave = t >> 6;          // 0..7
  const int wm   = wave & 3;        // co quarter (64 rows)
  const int wn   = wave >> 2;       // pix half (32 cols)

  const int p_img = p0 + lane;
  const int ph    = p_img / 56;
  const int pw    = p_img - ph * 56;
  const float* xn = x + (size_t)n * (CIN * HWS);
  const unsigned swzp = (unsigned)((lane & 7) << 4);

  f32x4 acc[4][2];
  const f32x4 zero4 = {0.f, 0.f, 0.f, 0.f};
#pragma unroll
  for (int m = 0; m < 4; ++m)
#pragma unroll
    for (int nn = 0; nn < 2; ++nn) acc[m][nn] = zero4;

  // ---- A stage: 256co x 64k bf16 (32KB) via global_load_lds, pre-swizzled src ----
  auto stageA = [&](int koff /*bytes into wb row*/, int buf) {
#pragma unroll
    for (int i = 0; i < 4; ++i) {
      unsigned o   = (unsigned)(i * 8192 + wave * 1024 + lane * 16);  // linear LDS byte
      unsigned row = o >> 7;      // co 0..255 (128B per row = 64 bf16)
      unsigned sb  = o & 127;
      const unsigned char* g = wb + (size_t)row * WROWB + (unsigned)koff
                                  + (sb ^ ((row & 7) << 4));
      unsigned char* l = smem + buf * 32768 + i * 8192 + wave * 1024;  // wave-uniform
      __builtin_amdgcn_global_load_lds((const GLOBAL_AS unsigned int*)g,
                                       (LDS_AS unsigned int*)l, 16, 0, 0);
    }
  };

  // ---- B stage: 64pix x 64ch fp32 gather -> bf16 -> swizzled LDS [pix][64ch] ----
  auto stageB = [&](int tap, int c0, int buf) {
    const int dh  = tap / 3 - 1;
    const int dw  = tap - (tap / 3) * 3 - 1;
    const int hh  = ph + dh;
    const int wwi = pw + dw;
    const bool valid = ((unsigned)hh < 56u) && ((unsigned)wwi < 56u);
    const float* s0 = xn + (size_t)(c0 + wave * 8) * HWS + hh * 56 + wwi;

    float f[8];
    if (valid) {
#pragma unroll
      for (int j = 0; j < 8; ++j) f[j] = s0[(size_t)j * HWS];
    } else {
#pragma unroll
      for (int j = 0; j < 8; ++j) f[j] = 0.f;
    }
    short8 v;
#pragma unroll
    for (int j = 0; j < 8; ++j) v[j] = (short)f2bf(f[j]);
    unsigned char* bB = smem + 65536 + buf * 8192;
    *(short8*)(bB + lane * 128 + ((unsigned)(wave * 16) ^ swzp)) = v;
  };

  // ---- compute one K-step (64) ----
  auto compute = [&](int buf) {
    const unsigned char* bA = smem + buf * 32768;
    const unsigned char* bB = smem + 65536 + buf * 8192;
    const int rl = lane & 15;
    const int kq = lane >> 4;
    const unsigned swz = (unsigned)((rl & 7) << 4);
#pragma unroll
    for (int ks = 0; ks < 2; ++ks) {
      const unsigned kb = (unsigned)(ks * 64 + kq * 16);
      short8 a[4], b[2];
#pragma unroll
      for (int m = 0; m < 4; ++m)
        a[m] = *(const short8*)(bA + (wm * 64 + m * 16 + rl) * 128 + (kb ^ swz));
#pragma unroll
      for (int nn = 0; nn < 2; ++nn)
        b[nn] = *(const short8*)(bB + (wn * 32 + nn * 16 + rl) * 128 + (kb ^ swz));
#pragma unroll
      for (int m = 0; m < 4; ++m)
#pragma unroll
        for (int nn = 0; nn < 2; ++nn)
          acc[m][nn] = __builtin_amdgcn_mfma_f32_16x16x32_bf16(a[m], b[nn], acc[m][nn], 0, 0, 0);
    }
  };

  // ---- 2-phase pipeline, s = cq*9 + tap (tap fastest -> x L2-hot) ----
  stageA(0, 0);
  stageB(0, 0, 0);
  __syncthreads();
  int buf = 0;
  for (int s = 0; s < NSTEP; ++s) {
    if (s < NSTEP - 1) {
      const int s1   = s + 1;
      const int cq1  = s1 / 9;
      const int tap1 = s1 - cq1 * 9;
      stageA(tap1 * 512 + cq1 * 128, buf ^ 1);
      stageB(tap1, cq1 * 64, buf ^ 1);
    }
    compute(buf);
    __syncthreads();
    buf ^= 1;
  }

  // ---- epilogue: bias + ReLU. C/D map: col=lane&15, row=(lane>>4)*4+j ----
  {
    const int rl = lane & 15;
    const int kq = lane >> 4;
    float* outn = out + (size_t)n * (CIN * HWS);
#pragma unroll
    for (int m = 0; m < 4; ++m) {
      const int row = wm * 64 + m * 16 + kq * 4;
#pragma unroll
      for (int nn = 0; nn < 2; ++nn) {
        const int col = p0 + wn * 32 + nn * 16 + rl;
        float* po = outn + (size_t)row * HWS + col;
#pragma unroll
        for (int j = 0; j < 4; ++j) {
          float v = acc[m][nn][j] + bias[row + j];
          po[(size_t)j * HWS] = fmaxf(v, 0.f);
        }
      }
    }
  }
}

extern "C" void kernel_launch(void* const* d_in, const int* in_sizes, int n_in,
                              void* d_out, int out_size, void* d_ws, size_t ws_size,
                              hipStream_t stream) {
  const float* x    = (const float*)d_in[0];
  const float* w    = (const float*)d_in[1];
  const float* bias = (const float*)d_in[2];
  float* out        = (float*)d_out;
  unsigned short* wb = (unsigned short*)d_ws;  // 1,179,648 B

  hipLaunchKernelGGL(wcvt_kernel, dim3(2304), dim3(256), 0, stream, w, wb);
  hipLaunchKernelGGL(conv_kernel, dim3(1568), dim3(512), 0, stream,
                     x, (const unsigned char*)d_ws, bias, out);
}